// Round 1
// baseline (127.910 us; speedup 1.0000x reference)
//
#include <hip/hip_runtime.h>
#include <math.h>

#define Bc 8
#define Hc 128
#define Wc 128
#define Cc 20
#define Gc 64
#define HWc (Hc*Wc)          // 16384

// workspace layout per image (floats), stride WS_STRIDE:
//  [0..63] by1  [64..127] bx1  [128..191] by2  [192..255] bx2
//  [256..319] fgy [320..383] fgx [384..447] isy [448..511] isx
//  [512..575] vf  [576..639] seg(int) [640..703] kpix(int)
//  [704] n_valid  [705..710] accums  [711] slice(int)
#define WS_STRIDE 768
#define WS_NV   704
#define WS_ACC  705
#define WS_SLICE 711

__global__ __launch_bounds__(64) void prep_kernel(
    const float* __restrict__ gt, const float* __restrict__ sy,
    const float* __restrict__ sx, float* __restrict__ ws)
{
  const int b = blockIdx.x;
  const int g = threadIdx.x;
  __shared__ float cy_s[Gc];
  __shared__ int slice_s;
  const float* row = gt + (size_t)(b*Gc + g)*7;
  const float cy = row[0];
  const float cx = row[1];
  cy_s[g] = cy;
  __syncthreads();
  if (g == 0) {  // argmin, first occurrence
    float mn = cy_s[0]; int idx = 0;
    for (int i = 1; i < Gc; ++i) { float v = cy_s[i]; if (v < mn) { mn = v; idx = i; } }
    slice_s = idx;
  }
  __syncthreads();
  const int slice = slice_s;
  float* wb = ws + (size_t)b*WS_STRIDE;
  int*  wbi = (int*)wb;
  wb[0*Gc+g] = (row[2]+0.5f)*0.25f;   // by1
  wb[1*Gc+g] = (row[3]+0.5f)*0.25f;   // bx1
  wb[2*Gc+g] = (row[4]+0.5f)*0.25f;   // by2
  wb[3*Gc+g] = (row[5]+0.5f)*0.25f;   // bx2
  wb[4*Gc+g] = floorf((cy+0.5f)*0.25f); // floor(gy)
  wb[5*Gc+g] = floorf((cx+0.5f)*0.25f); // floor(gx)
  wb[6*Gc+g] = 1.0f / sy[b*Gc+g];
  wb[7*Gc+g] = 1.0f / sx[b*Gc+g];
  const float vf = (g < slice) ? 1.0f : 0.0f;
  wb[8*Gc+g] = vf;
  const int cid = (int)row[6] - 1;
  wbi[9*Gc+g] = (vf > 0.0f && cid >= 0 && cid < Cc) ? cid : Cc;
  int kpy = (int)floorf(cy*0.25f); kpy = kpy < 0 ? 0 : (kpy > Hc-1 ? Hc-1 : kpy);
  int kpx = (int)floorf(cx*0.25f); kpx = kpx < 0 ? 0 : (kpx > Wc-1 ? Wc-1 : kpx);
  wbi[10*Gc+g] = kpy*Wc + kpx;
  if (g == 0) { wb[WS_NV] = fmaxf((float)slice, 1.0f); wbi[WS_SLICE] = slice; }
  if (g < 6) wb[WS_ACC+g] = 0.0f;     // zero accumulators (ws is re-poisoned each launch)
}

__device__ __forceinline__ float logsig(float x) {
  // stable log(sigmoid(x)) = min(x,0) - log1p(exp(-|x|))
  return fminf(x, 0.0f) - log1pf(__expf(-fabsf(x)));
}
__device__ __forceinline__ float sigmoidf_(float x) {
  return 1.0f / (1.0f + __expf(-x));
}
__device__ __forceinline__ float wave_sum(float v) {
  #pragma unroll
  for (int o = 32; o > 0; o >>= 1) v += __shfl_down(v, o, 64);
  return v;
}

__global__ __launch_bounds__(256) void main_kernel(
  const float* __restrict__ kpt, const float* __restrict__ preg,
  const float* __restrict__ fpn, const float* __restrict__ masks,
  float* __restrict__ ws)
{
  __shared__ float s_pg[704];
  __shared__ float s_rmax[256*21];   // per-thread rmax[20], stride 21 (odd -> bank-conflict-free)
  __shared__ float s_part[4][6];

  const int tid = threadIdx.x;
  const int b   = blockIdx.x >> 6;           // 64 blocks of 256 per image
  const int pix = blockIdx.x*256 + tid;
  const int hw  = pix & (HWc-1);
  const int h = hw >> 7, w = hw & (Wc-1);

  float* wb = ws + (size_t)b*WS_STRIDE;
  { const int* src = (const int*)wb; int* dst = (int*)s_pg;
    for (int i = tid; i < 704; i += 256) dst[i] = src[i]; }
  float* rme = s_rmax + tid*21;
  #pragma unroll
  for (int c = 0; c < 21; ++c) rme[c] = 0.0f;
  __syncthreads();

  const float* s_by1 = s_pg;
  const float* s_bx1 = s_pg + 64;
  const float* s_by2 = s_pg + 128;
  const float* s_bx2 = s_pg + 192;
  const float* s_fgy = s_pg + 256;
  const float* s_fgx = s_pg + 320;
  const float* s_isy = s_pg + 384;
  const float* s_isx = s_pg + 448;
  const int*   s_seg = (const int*)(s_pg + 576);
  const int*   s_kpx = (const int*)(s_pg + 640);
  const int nslice = ((const int*)wb)[WS_SLICE];

  const float wx = w + 0.5f, hy = h + 0.5f;       // grid centers
  const float px_ = (float)w, py_ = (float)h;     // grid - 0.5
  const float* mrow = masks + (size_t)pix * Gc;

  float amin = 3.0e38f; int gmin = -1;
  float loc = 0.0f, iou_red = 0.0f;
  unsigned kpmask = 0;

  // single pass over valid gts (g >= nslice contribute nothing)
  for (int g0 = 0; g0 < nslice; g0 += 4) {
    const float4 m4 = *(const float4*)(mrow + g0);
    #pragma unroll
    for (int j = 0; j < 4; ++j) {
      const int g = g0 + j;
      if (g >= nslice) break;
      const float m = (j==0) ? m4.x : (j==1) ? m4.y : (j==2) ? m4.z : m4.w;
      const float dl = wx - s_bx1[g], dr = s_bx2[g] - wx;
      const float dt = hy - s_by1[g], db = s_by2[g] - hy;
      const bool inbox = (dl > 0.0f) & (dr > 0.0f) & (dt > 0.0f) & (db > 0.0f);
      const float hm = inbox ? m : 0.0f;          // vf==1 inside loop
      const float area = (dl*hm + dr*hm) * (dt*hm + db*hm);
      const float ap = area + (1.0f - hm)*1e8f;   // padded area
      if (ap < amin) { amin = ap; gmin = g; }     // first strict min == jnp tie behavior (ties measure-zero)
      loc = fmaxf(loc, hm);
      const float dy = py_ - s_fgy[g], dx = px_ - s_fgx[g];
      const float red = __expf(-0.5f*(dy*dy*s_isy[g] + dx*dx*s_isx[g]));
      iou_red = fmaxf(iou_red, red);
      const int c = s_seg[g];                     // wave-uniform branch
      if (c < Cc) {
        if (red > rme[c]) rme[c] = red;
        if (s_kpx[g] == hw) kpmask |= (1u << c);
      }
    }
  }

  // dist_mask is nonzero only at gmin (value = loc)
  float dlm=0.0f, drm=0.0f, dtm=0.0f, dbm=0.0f; int cmin = Cc; float hmval = 0.0f;
  if (loc > 0.0f && gmin >= 0) {
    const float m = mrow[gmin];                   // L1-hot
    const float dl = wx - s_bx1[gmin], dr = s_bx2[gmin] - wx;
    const float dt = hy - s_by1[gmin], db = s_by2[gmin] - hy;
    dlm = dl*m*loc; drm = dr*m*loc; dtm = dt*m*loc; dbm = db*m*loc;
    cmin = s_seg[gmin];
    hmval = loc;
  }

  const float4 p4 = *(const float4*)(preg + (size_t)pix*4);
  const float inter = (fminf(dlm,p4.x)+fminf(drm,p4.y)) * (fminf(dtm,p4.z)+fminf(dbm,p4.w));
  const float uni = (dlm+drm)*(dtm+dbm) + (p4.x+p4.y)*(p4.z+p4.w) - inter;
  const float iou = inter / (uni + 1e-12f);
  const float t_iou = -logf(iou + 1e-12f) * loc * (iou_red*4.0f + 1.0f);

  float grav = 0.0f, hpos = 0.0f, hneg = 0.0f, shg = 0.0f;
  const float* kq = kpt + (size_t)pix*Cc;
  const float* fq = fpn + (size_t)pix*Cc;
  #pragma unroll
  for (int c = 0; c < Cc; ++c) {
    const float x   = kq[c];
    const float s   = sigmoidf_(x);
    const float lsx = logsig(x);
    const float rmax = rme[c];
    const float kpv  = ((kpmask >> c) & 1u) ? 1.0f : 0.0f;
    const float om  = 1.0f - rmax;
    const float om4 = (om*om)*(om*om);
    const float oms = 1.0f - s;
    const float pos_t = -(oms*oms)*lsx;
    const float neg_t = -om4*(s*s)*(lsx - x);
    grav += pos_t*kpv + neg_t*(1.0f - kpv);

    const float fx  = fq[c];
    const float sf  = sigmoidf_(fx);
    const float lsf = logsig(fx);
    const float hg  = (c == cmin) ? hmval : 0.0f;
    const float osf = 1.0f - sf;
    hpos += -10.0f*(osf*osf)*lsf*hg;
    hneg += -10.0f*(sf*sf)*(lsf - fx)*(1.0f - hg);
    shg  += hg;
  }

  // block reduction: 6 scalars
  float v0 = wave_sum(t_iou);
  float v1 = wave_sum(loc);
  float v2 = wave_sum(grav);
  float v3 = wave_sum(hpos);
  float v4 = wave_sum(hneg);
  float v5 = wave_sum(shg);
  const int wv = tid >> 6, ln = tid & 63;
  if (ln == 0) {
    s_part[wv][0]=v0; s_part[wv][1]=v1; s_part[wv][2]=v2;
    s_part[wv][3]=v3; s_part[wv][4]=v4; s_part[wv][5]=v5;
  }
  __syncthreads();
  if (tid < 6) {
    const float a = s_part[0][tid] + s_part[1][tid] + s_part[2][tid] + s_part[3][tid];
    atomicAdd(wb + WS_ACC + tid, a);
  }
}

__global__ __launch_bounds__(64) void fin_kernel(const float* __restrict__ ws,
                                                 float* __restrict__ out)
{
  const int b = threadIdx.x;
  float total = 0.0f;
  if (b < Bc) {
    const float* wb = ws + (size_t)b*WS_STRIDE;
    const float iou_loss = wb[WS_ACC+0];
    const float s_loc    = wb[WS_ACC+1];
    const float grav     = wb[WS_ACC+2];
    const float hposs    = wb[WS_ACC+3];
    const float hnegs    = wb[WS_ACC+4];
    const float shg      = wb[WS_ACC+5];
    const float nv       = wb[WS_NV];
    const float hm_loss  = hnegs / ((float)(HWc*Cc) - shg);
    const bool  cond     = (shg != 0.0f);
    const float safe_hg  = cond ? shg : 1.0f;
    const float safe_loc = (s_loc > 0.0f) ? s_loc : 1.0f;
    const float hm2      = hm_loss + hposs/safe_hg;
    total = cond ? (iou_loss/safe_loc + grav/nv + hm2) : hm_loss;
  }
  #pragma unroll
  for (int o = 4; o > 0; o >>= 1) total += __shfl_down(total, o, 64);
  if (b == 0) out[0] = total * (1.0f/(float)Bc);
}

extern "C" void kernel_launch(void* const* d_in, const int* in_sizes, int n_in,
                              void* d_out, int out_size, void* d_ws, size_t ws_size,
                              hipStream_t stream) {
  const float* kpt  = (const float*)d_in[0];  // keypoints  [B,H,W,C]
  const float* preg = (const float*)d_in[1];  // preg       [B,H,W,4]
  const float* fpn  = (const float*)d_in[2];  // fpn        [B,H,W,C]
  const float* gt   = (const float*)d_in[3];  // gt         [B,G,7]
  const float* mk   = (const float*)d_in[4];  // masks      [B,H,W,G]
  const float* sy   = (const float*)d_in[5];  // scalar_y   [B,G]
  const float* sx   = (const float*)d_in[6];  // scalar_x   [B,G]
  float* ws  = (float*)d_ws;
  float* out = (float*)d_out;

  prep_kernel<<<Bc, 64, 0, stream>>>(gt, sy, sx, ws);
  main_kernel<<<(Bc*HWc)/256, 256, 0, stream>>>(kpt, preg, fpn, mk, ws);
  fin_kernel<<<1, 64, 0, stream>>>(ws, out);
}